// Round 14
// baseline (986.431 us; speedup 1.0000x reference)
//
#include <hip/hip_runtime.h>
#include <stdint.h>
#include <math.h>

#define DM   128
#define NH   8
#define EHD  16
#define NLAY 5
#define DFF  64
#define NREP 128
#define NB   8
#define SL   4096
#define NC   27
#define NBH  (NB*NH)      // 64
#define NROWS (NB*SL)     // 32768
#define ACH  4            // attn KV chunks

typedef _Float16 f16;
typedef f16 f16x8 __attribute__((ext_vector_type(8)));
typedef float f32x16 __attribute__((ext_vector_type(16)));

// ---------------- threefry2x32 (JAX-exact) ----------------
__device__ __forceinline__ uint32_t rotl32(uint32_t v, int d) {
  return (v << d) | (v >> (32 - d));
}

__device__ __forceinline__ void tf2x32(uint32_t k0, uint32_t k1,
                                       uint32_t x0, uint32_t x1,
                                       uint32_t &o0, uint32_t &o1) {
  uint32_t ks2 = k0 ^ k1 ^ 0x1BD11BDAu;
  x0 += k0; x1 += k1;
#define TFR(r) { x0 += x1; x1 = rotl32(x1, (r)); x1 ^= x0; }
  TFR(13) TFR(15) TFR(26) TFR(6)
  x0 += k1; x1 += ks2 + 1u;
  TFR(17) TFR(29) TFR(16) TFR(24)
  x0 += ks2; x1 += k0 + 2u;
  TFR(13) TFR(15) TFR(26) TFR(6)
  x0 += k0; x1 += k1 + 3u;
  TFR(17) TFR(29) TFR(16) TFR(24)
  x0 += k1; x1 += ks2 + 4u;
  TFR(13) TFR(15) TFR(26) TFR(6)
  x0 += ks2; x1 += k0 + 5u;
#undef TFR
  o0 = x0; o1 = x1;
}

// bits[i] for flat counter i = l*NC + u
__global__ void gen_bits_kernel(uint32_t* __restrict__ bits, int layer) {
  int i = blockIdx.x * blockDim.x + threadIdx.x;
  if (i >= SL * NC) return;
  uint32_t ka, kb, k2a, k2b, y0, y1;
  tf2x32(0u, 42u, 0u, (uint32_t)layer, ka, kb);
  tf2x32(ka, kb, 0u, 1u, k2a, k2b);
  tf2x32(k2a, k2b, 0u, (uint32_t)i, y0, y1);
  bits[i] = y0 ^ y1;
}

// ---------------- x[b,d,l] -> h[b,l,d], LDS-tiled ----------------
__global__ __launch_bounds__(256) void transpose_x_kernel(const float* __restrict__ x,
                                                          float* __restrict__ h) {
  __shared__ float t[32][33];
  int tid = threadIdx.x;
  int tx = tid & 31, ty = tid >> 5;
  int l0 = blockIdx.x * 32, d0 = blockIdx.y * 32, b = blockIdx.z;
#pragma unroll
  for (int j = 0; j < 4; ++j) {
    int d = d0 + ty + 8 * j;
    t[ty + 8 * j][tx] = x[((size_t)b * DM + d) * SL + l0 + tx];
  }
  __syncthreads();
#pragma unroll
  for (int j = 0; j < 4; ++j) {
    int l = l0 + ty + 8 * j;
    h[((size_t)b * SL + l) * DM + d0 + tx] = t[tx][ty + 8 * j];
  }
}

// ---------------- weight prep: fp32 -> f16 hi ----------------
#define PACK_TOTAL 425984
__global__ __launch_bounds__(256) void prep_weights(
    const float* __restrict__ Wq, const float* __restrict__ Wk,
    const float* __restrict__ Wv, const float* __restrict__ Wo,
    const float* __restrict__ W1, const float* __restrict__ W2,
    const float* __restrict__ Wp, f16* __restrict__ phi) {
  int idx = blockIdx.x * 256 + threadIdx.x;
  if (idx >= PACK_TOTAL) return;
  const float* src; int K, KS16, lsh; int f; bool transp = false;
  if (idx >= 409600) { f = idx - 409600; src = Wp; K = 128; KS16 = 8; lsh = 3; transp = true; }
  else {
    int layer = idx / 81920; int r = idx - layer * 81920;
    if      (r < 16384) { src = Wq + layer * 16384; f = r;         K = 128; KS16 = 8; lsh = 3; }
    else if (r < 32768) { src = Wk + layer * 16384; f = r - 16384; K = 128; KS16 = 8; lsh = 3; }
    else if (r < 49152) { src = Wv + layer * 16384; f = r - 32768; K = 128; KS16 = 8; lsh = 3; }
    else if (r < 65536) { src = Wo + layer * 16384; f = r - 49152; K = 128; KS16 = 8; lsh = 3; }
    else if (r < 73728) { src = W1 + layer * 8192;  f = r - 65536; K = 128; KS16 = 8; lsh = 3; }
    else                { src = W2 + layer * 8192;  f = r - 73728; K = 64;  KS16 = 4; lsh = 2; }
  }
  int j = f & 7, lane = (f >> 3) & 63, rest = f >> 9;
  int ks = rest & (KS16 - 1), nt = rest >> lsh;
  int n = nt * 32 + (lane & 31);
  int kk = ks * 16 + ((lane >> 5) & 1) * 8 + j;
  float x = transp ? src[(size_t)kk * 128 + n] : src[(size_t)n * K + kk];
  phi[idx] = (f16)x;
}

// ---------------- split-fp16 MFMA GEMM (2-pass: Ahi*Bhi + Alo*Bhi) ----------------
template<int NT32, int KS16, int SRC, int EPI>
__global__ __launch_bounds__(256, 2) void gemm_fused(
    const float* __restrict__ Asrc, const f16* __restrict__ phi,
    const float* __restrict__ bias0, const float* __restrict__ bias1,
    const float* __restrict__ bias2,
    float* out0, float* out1, float* out2,
    const float* __restrict__ gw, const float* __restrict__ gb,
    const float* hres) {
  constexpr int NGW = NT32 / 2;
  constexpr int K = KS16 * 16;
  __shared__ f16x8 Alds[2 * 2 * KS16 * 64];
  __shared__ f16x8 Blds[NT32 * KS16 * 64];
  __shared__ float red[64 * 4];
  int tid = threadIdx.x, lane = tid & 63, wid = tid >> 6;
  int mg = wid >> 1, ng = wid & 1;
  int row0 = blockIdx.x * 64;

  // ---- stage A (hi+lo) ----
  if constexpr (SRC == 0 || SRC == 1) {
    constexpr int OCT = 64 * (K / 8);
    for (int o = tid; o < OCT; o += 256) {
      int row = o / (K / 8);
      int k0 = (o % (K / 8)) * 8;
      float4 f0, f1;
      if constexpr (SRC == 0) {
        const float* s = Asrc + (size_t)(row0 + row) * K + k0;
        f0 = *(const float4*)(s);
        f1 = *(const float4*)(s + 4);
      } else {
        int gr = row0 + row; int bb = gr >> 12, ll = gr & (SL - 1);
        int head = k0 >> 4, e0 = k0 & 15;
        const float* s = Asrc + (((size_t)(bb * NH + head) * SL + ll) * EHD + e0);
        f0 = *(const float4*)(s);
        f1 = *(const float4*)(s + 4);
      }
      f16x8 vh, vl;
      float xs[8] = {f0.x, f0.y, f0.z, f0.w, f1.x, f1.y, f1.z, f1.w};
#pragma unroll
      for (int j = 0; j < 8; ++j) {
        f16 hh = (f16)xs[j];
        vh[j] = hh;
        vl[j] = (f16)(xs[j] - (float)hh);
      }
      int al = (row & 31) | (((k0 >> 3) & 1) << 5);
      int ks = k0 >> 4, mt = row >> 5;
      Alds[((0 * 2 + mt) * KS16 + ks) * 64 + al] = vh;
      Alds[((1 * 2 + mt) * KS16 + ks) * 64 + al] = vl;
    }
  } else {  // SRC == 3 : h rows + final LayerNorm before packing
    int row = tid >> 2, q4 = tid & 3;
    const float* s = Asrc + (size_t)(row0 + row) * 128 + q4 * 32;
    float r[32];
#pragma unroll
    for (int i = 0; i < 8; ++i) {
      float4 f = *(const float4*)(s + 4 * i);
      r[4 * i] = f.x; r[4 * i + 1] = f.y; r[4 * i + 2] = f.z; r[4 * i + 3] = f.w;
    }
    float sm = 0.f, s2 = 0.f;
#pragma unroll
    for (int i = 0; i < 32; ++i) { sm += r[i]; s2 += r[i] * r[i]; }
    sm += __shfl_xor(sm, 1, 4); sm += __shfl_xor(sm, 2, 4);
    s2 += __shfl_xor(s2, 1, 4); s2 += __shfl_xor(s2, 2, 4);
    float mean = sm * (1.f / 128.f);
    float var = s2 * (1.f / 128.f) - mean * mean;
    float rstd = 1.0f / sqrtf(var + 1e-5f);
#pragma unroll
    for (int i = 0; i < 32; ++i) {
      int kk = q4 * 32 + i;
      r[i] = (r[i] - mean) * rstd * gw[kk] + gb[kk];
    }
#pragma unroll
    for (int i = 0; i < 4; ++i) {
      int k0 = q4 * 32 + i * 8;
      f16x8 vh, vl;
#pragma unroll
      for (int j = 0; j < 8; ++j) {
        float x = r[8 * i + j];
        f16 hh = (f16)x;
        vh[j] = hh;
        vl[j] = (f16)(x - (float)hh);
      }
      int al = (row & 31) | (((k0 >> 3) & 1) << 5);
      int ks = k0 >> 4, mt = row >> 5;
      Alds[((0 * 2 + mt) * KS16 + ks) * 64 + al] = vh;
      Alds[((1 * 2 + mt) * KS16 + ks) * 64 + al] = vl;
    }
  }

  constexpr int NMAT = (EPI == 0) ? 3 : 1;
  constexpr int BCNT = NT32 * KS16 * 64;  // f16x8 (=float4) count

#define STAGE_B(SRCPTR)                                        \
  {                                                            \
    const float4* bsrc = (const float4*)(SRCPTR);              \
    float4* bdst = (float4*)Blds;                              \
    _Pragma("unroll")                                          \
    for (int i = 0; i < BCNT / 256; ++i) bdst[tid + i * 256] = bsrc[tid + i * 256]; \
  }

#define GEMM_PASS(ASEL)                                                         \
  _Pragma("unroll")                                                             \
  for (int ks = 0; ks < KS16; ++ks) {                                           \
    f16x8 afr = Alds[(((ASEL) * 2 + mg) * KS16 + ks) * 64 + lane];              \
    _Pragma("unroll")                                                           \
    for (int g = 0; g < NGW; ++g) {                                             \
      f16x8 bfr = Blds[((ng * NGW + g) * KS16 + ks) * 64 + lane];               \
      acc[g] = __builtin_amdgcn_mfma_f32_32x32x16_f16(afr, bfr, acc[g], 0, 0, 0); \
    }                                                                           \
  }

  for (int m = 0; m < NMAT; ++m) {
    if (m) __syncthreads();
    STAGE_B(phi + m * 16384)
    __syncthreads();
    f32x16 acc[NGW];
#pragma unroll
    for (int g = 0; g < NGW; ++g)
#pragma unroll
      for (int j = 0; j < 16; ++j) acc[g][j] = 0.f;
    GEMM_PASS(0)
    GEMM_PASS(1)

    // ---- epilogue ----
    int hi4 = 4 * (lane >> 5);
    if constexpr (EPI == 0) {
      const float* bm = (m == 0) ? bias0 : (m == 1) ? bias1 : bias2;
      float* om = (m == 0) ? out0 : (m == 1) ? out1 : out2;
#pragma unroll
      for (int g = 0; g < NGW; ++g) {
        int col = ng * (NGW * 32) + g * 32 + (lane & 31);
        float bv = bm[col];
        int head = col >> 4, e = col & 15;
#pragma unroll
        for (int reg = 0; reg < 16; ++reg) {
          int row_l = (reg & 3) + 8 * (reg >> 2) + hi4;
          int grow = row0 + mg * 32 + row_l;
          int bb = grow >> 12, ll = grow & (SL - 1);
          om[((size_t)(bb * NH + head) * SL + ll) * EHD + e] = acc[g][reg] + bv;
        }
      }
    } else if constexpr (EPI == 3) {
#pragma unroll
      for (int g = 0; g < NGW; ++g) {
        int col = ng * (NGW * 32) + g * 32 + (lane & 31);
        float bv = bias0[col];
#pragma unroll
        for (int reg = 0; reg < 16; ++reg) {
          int row_l = (reg & 3) + 8 * (reg >> 2) + hi4;
          int grow = row0 + mg * 32 + row_l;
          int bb = grow >> 12, ll = grow & (SL - 1);
          out0[((size_t)(bb * NREP + col)) * SL + ll] = acc[g][reg] + bv;
        }
      }
    } else {  // EPI == 1: residual + LayerNorm -> h
      float bv[2], gwv[2], gbv[2];
#pragma unroll
      for (int g = 0; g < NGW; ++g) {
        int col = ng * (NGW * 32) + g * 32 + (lane & 31);
        bv[g] = bias0[col]; gwv[g] = gw[col]; gbv[g] = gb[col];
      }
      float ps[16], pq[16];
#pragma unroll
      for (int reg = 0; reg < 16; ++reg) {
        int row_l = (reg & 3) + 8 * (reg >> 2) + hi4;
        int grow = row0 + mg * 32 + row_l;
        float vsum = 0.f, qsum = 0.f;
#pragma unroll
        for (int g = 0; g < NGW; ++g) {
          int col = ng * (NGW * 32) + g * 32 + (lane & 31);
          float t = acc[g][reg] + bv[g] + hres[(size_t)grow * DM + col];
          acc[g][reg] = t;
          vsum += t; qsum += t * t;
        }
        vsum += __shfl_xor(vsum, 1, 32); qsum += __shfl_xor(qsum, 1, 32);
        vsum += __shfl_xor(vsum, 2, 32); qsum += __shfl_xor(qsum, 2, 32);
        vsum += __shfl_xor(vsum, 4, 32); qsum += __shfl_xor(qsum, 4, 32);
        vsum += __shfl_xor(vsum, 8, 32); qsum += __shfl_xor(qsum, 8, 32);
        vsum += __shfl_xor(vsum, 16, 32); qsum += __shfl_xor(qsum, 16, 32);
        ps[reg] = vsum; pq[reg] = qsum;
      }
      __syncthreads();
      if ((lane & 31) == 0) {
#pragma unroll
        for (int reg = 0; reg < 16; ++reg) {
          int row_l = (reg & 3) + 8 * (reg >> 2) + hi4;
          int rl = mg * 32 + row_l;
          red[rl * 4 + ng * 2 + 0] = ps[reg];
          red[rl * 4 + ng * 2 + 1] = pq[reg];
        }
      }
      __syncthreads();
#pragma unroll
      for (int reg = 0; reg < 16; ++reg) {
        int row_l = (reg & 3) + 8 * (reg >> 2) + hi4;
        int rl = mg * 32 + row_l;
        int grow = row0 + rl;
        float st = red[rl * 4 + 0] + red[rl * 4 + 2];
        float qt = red[rl * 4 + 1] + red[rl * 4 + 3];
        float mean = st * (1.f / 128.f);
        float var = qt * (1.f / 128.f) - mean * mean;
        float rstd = 1.0f / sqrtf(var + 1e-5f);
#pragma unroll
        for (int g = 0; g < NGW; ++g) {
          int col = ng * (NGW * 32) + g * 32 + (lane & 31);
          out0[(size_t)grow * DM + col] = (acc[g][reg] - mean) * rstd * gwv[g] + gbv[g];
        }
      }
    }
  }
#undef STAGE_B
#undef GEMM_PASS
}

// ---------------- fused FFN (2-pass GEMMs) ----------------
__global__ __launch_bounds__(256, 2) void gemm_ffn(
    const float* __restrict__ h,
    const f16* __restrict__ w1hi, const f16* __restrict__ w2hi,
    const float* __restrict__ b1, const float* __restrict__ b2,
    const float* __restrict__ gw, const float* __restrict__ gb,
    float* __restrict__ hout) {
  __shared__ f16x8 AldsH[2 * 2 * 8 * 64];   // 32KB
  __shared__ f16x8 Blds1[2 * 8 * 64];       // 16KB
  __shared__ float ybuf[64 * 64];           // 16KB
  __shared__ float red[64 * 4];
  f16x8* Alds2 = AldsH;
  f16x8* Blds2 = AldsH + 1024;
  int tid = threadIdx.x, lane = tid & 63, wid = tid >> 6;
  int mg = wid >> 1, ng = wid & 1;
  int row0 = blockIdx.x * 64;
  int hi4 = 4 * (lane >> 5);

  for (int o = tid; o < 64 * 16; o += 256) {
    int row = o >> 4;
    int k0 = (o & 15) * 8;
    const float* s = h + (size_t)(row0 + row) * 128 + k0;
    float4 f0 = *(const float4*)(s);
    float4 f1 = *(const float4*)(s + 4);
    f16x8 vh, vl;
    float xs[8] = {f0.x, f0.y, f0.z, f0.w, f1.x, f1.y, f1.z, f1.w};
#pragma unroll
    for (int j = 0; j < 8; ++j) {
      f16 hh = (f16)xs[j];
      vh[j] = hh;
      vl[j] = (f16)(xs[j] - (float)hh);
    }
    int al = (row & 31) | (((k0 >> 3) & 1) << 5);
    int ks = k0 >> 4, mt = row >> 5;
    AldsH[((0 * 2 + mt) * 8 + ks) * 64 + al] = vh;
    AldsH[((1 * 2 + mt) * 8 + ks) * 64 + al] = vl;
  }
  {
    const float4* bsrc = (const float4*)w1hi;
    float4* bdst = (float4*)Blds1;
#pragma unroll
    for (int i = 0; i < 4; ++i) bdst[tid + i * 256] = bsrc[tid + i * 256];
  }
  __syncthreads();
  f32x16 acc1;
#pragma unroll
  for (int j = 0; j < 16; ++j) acc1[j] = 0.f;
#pragma unroll
  for (int asel = 0; asel < 2; ++asel)
#pragma unroll
    for (int ks = 0; ks < 8; ++ks) {
      f16x8 afr = AldsH[((asel * 2 + mg) * 8 + ks) * 64 + lane];
      f16x8 bfr = Blds1[(ng * 8 + ks) * 64 + lane];
      acc1 = __builtin_amdgcn_mfma_f32_32x32x16_f16(afr, bfr, acc1, 0, 0, 0);
    }
  {
    int col = ng * 32 + (lane & 31);
    float bv = b1[col];
    const float is2 = 0.707106781186547524f;
#pragma unroll
    for (int reg = 0; reg < 16; ++reg) {
      int row_l = (reg & 3) + 8 * (reg >> 2) + hi4 + mg * 32;
      float a = acc1[reg] + bv;
      ybuf[row_l * 64 + col] = 0.5f * a * (1.f + erff(a * is2));
    }
  }
  __syncthreads();   // ybuf complete AND all GEMM1 reads of AldsH/Blds1 done
  for (int o = tid; o < 64 * 8; o += 256) {
    int row = o >> 3;
    int k0 = (o & 7) * 8;
    f16x8 vh, vl;
#pragma unroll
    for (int j = 0; j < 8; ++j) {
      float x = ybuf[row * 64 + k0 + j];
      f16 hh = (f16)x;
      vh[j] = hh;
      vl[j] = (f16)(x - (float)hh);
    }
    int al = (row & 31) | (((k0 >> 3) & 1) << 5);
    int ks = k0 >> 4, mt = row >> 5;
    Alds2[((0 * 2 + mt) * 4 + ks) * 64 + al] = vh;
    Alds2[((1 * 2 + mt) * 4 + ks) * 64 + al] = vl;
  }
  {
    const float4* bsrc = (const float4*)w2hi;
    float4* bdst = (float4*)Blds2;
#pragma unroll
    for (int i = 0; i < 4; ++i) bdst[tid + i * 256] = bsrc[tid + i * 256];
  }
  __syncthreads();
  f32x16 acc[2];
#pragma unroll
  for (int g = 0; g < 2; ++g)
#pragma unroll
    for (int j = 0; j < 16; ++j) acc[g][j] = 0.f;
#pragma unroll
  for (int asel = 0; asel < 2; ++asel)
#pragma unroll
    for (int ks = 0; ks < 4; ++ks) {
      f16x8 afr = Alds2[((asel * 2 + mg) * 4 + ks) * 64 + lane];
#pragma unroll
      for (int g = 0; g < 2; ++g) {
        f16x8 bfr = Blds2[((ng * 2 + g) * 4 + ks) * 64 + lane];
        acc[g] = __builtin_amdgcn_mfma_f32_32x32x16_f16(afr, bfr, acc[g], 0, 0, 0);
      }
    }
  {
    float bv[2], gwv[2], gbv[2];
#pragma unroll
    for (int g = 0; g < 2; ++g) {
      int col = ng * 64 + g * 32 + (lane & 31);
      bv[g] = b2[col]; gwv[g] = gw[col]; gbv[g] = gb[col];
    }
    float ps[16], pq[16];
#pragma unroll
    for (int reg = 0; reg < 16; ++reg) {
      int row_l = (reg & 3) + 8 * (reg >> 2) + hi4;
      int grow = row0 + mg * 32 + row_l;
      float vsum = 0.f, qsum = 0.f;
#pragma unroll
      for (int g = 0; g < 2; ++g) {
        int col = ng * 64 + g * 32 + (lane & 31);
        float t = acc[g][reg] + bv[g] + h[(size_t)grow * DM + col];
        acc[g][reg] = t;
        vsum += t; qsum += t * t;
      }
      vsum += __shfl_xor(vsum, 1, 32); qsum += __shfl_xor(qsum, 1, 32);
      vsum += __shfl_xor(vsum, 2, 32); qsum += __shfl_xor(qsum, 2, 32);
      vsum += __shfl_xor(vsum, 4, 32); qsum += __shfl_xor(qsum, 4, 32);
      vsum += __shfl_xor(vsum, 8, 32); qsum += __shfl_xor(qsum, 8, 32);
      vsum += __shfl_xor(vsum, 16, 32); qsum += __shfl_xor(qsum, 16, 32);
      ps[reg] = vsum; pq[reg] = qsum;
    }
    __syncthreads();
    if ((lane & 31) == 0) {
#pragma unroll
      for (int reg = 0; reg < 16; ++reg) {
        int row_l = (reg & 3) + 8 * (reg >> 2) + hi4;
        int rl = mg * 32 + row_l;
        red[rl * 4 + ng * 2 + 0] = ps[reg];
        red[rl * 4 + ng * 2 + 1] = pq[reg];
      }
    }
    __syncthreads();
#pragma unroll
    for (int reg = 0; reg < 16; ++reg) {
      int row_l = (reg & 3) + 8 * (reg >> 2) + hi4;
      int rl = mg * 32 + row_l;
      int grow = row0 + rl;
      float st = red[rl * 4 + 0] + red[rl * 4 + 2];
      float qt = red[rl * 4 + 1] + red[rl * 4 + 3];
      float mean = st * (1.f / 128.f);
      float var = qt * (1.f / 128.f) - mean * mean;
      float rstd = 1.0f / sqrtf(var + 1e-5f);
#pragma unroll
      for (int g = 0; g < 2; ++g) {
        int col = ng * 64 + g * 32 + (lane & 31);
        hout[(size_t)grow * DM + col] = (acc[g][reg] - mean) * rstd * gwv[g] + gbv[g];
      }
    }
  }
}

// ---------------- sampled scores -> M (8 queries/wave, 4 samples/lane) -------------
// lane = q8*8 + s8; q8 = query within wave, s8 = sample slot (handles u = s8+8i).
// grid = NBH*SL/32; blk&63 = bh (XCD-local K). Block 256 = 4 waves = 32 queries.
__global__ __launch_bounds__(256, 4) void sampM_kernel(const float* __restrict__ q,
    const float* __restrict__ k, const uint32_t* __restrict__ bits,
    float* __restrict__ M) {
  int tid = threadIdx.x;
  int lane = tid & 63, wave = tid >> 6;
  int bh = blockIdx.x & 63;
  int q8 = lane >> 3, s8 = lane & 7;
  int l = (blockIdx.x >> 6) * 32 + wave * 8 + q8;
  const float* qr = q + ((size_t)bh * SL + l) * EHD;
  float4 qv0 = *(const float4*)(qr + 0);
  float4 qv1 = *(const float4*)(qr + 4);
  float4 qv2 = *(const float4*)(qr + 8);
  float4 qv3 = *(const float4*)(qr + 12);
  int ki[4];
#pragma unroll
  for (int i = 0; i < 4; ++i) {
    int u = s8 + 8 * i;
    ki[i] = (u < NC) ? (int)(bits[l * NC + u] & (SL - 1)) : -1;
  }
  const float* kb = k + (size_t)bh * SL * EHD;
  float4 kr[4][4];
#pragma unroll
  for (int i = 0; i < 4; ++i) {
    const float* kp = kb + (size_t)(ki[i] < 0 ? 0 : ki[i]) * EHD;
#pragma unroll
    for (int j = 0; j < 4; ++j) kr[i][j] = *(const float4*)(kp + 4 * j);
  }
  float mx = -INFINITY, sm = 0.f;
#pragma unroll
  for (int i = 0; i < 4; ++i) {
    float s = qv0.x*kr[i][0].x + qv0.y*kr[i][0].y + qv0.z*kr[i][0].z + qv0.w*kr[i][0].w
            + qv1.x*kr[i][1].x + qv1.y*kr[i][1].y + qv1.z*kr[i][1].z + qv1.w*kr[i][1].w
            + qv2.x*kr[i][2].x + qv2.y*kr[i][2].y + qv2.z*kr[i][2].z + qv2.w*kr[i][2].w
            + qv3.x*kr[i][3].x + qv3.y*kr[i][3].y + qv3.z*kr[i][3].z + qv3.w*kr[i][3].w;
    if (ki[i] >= 0) { mx = fmaxf(mx, s); sm += s; }
  }
#pragma unroll
  for (int off = 1; off < 8; off <<= 1) {
    mx = fmaxf(mx, __shfl_xor(mx, off, 8));
    sm += __shfl_xor(sm, off, 8);
  }
  if (s8 == 0) M[(size_t)bh * SL + l] = mx - sm * (1.0f / (float)SL);
}

// ---------------- top-k (iterative argmax, wave butterfly, stable ties) ----------------
__global__ __launch_bounds__(256) void topk_kernel(const float* __restrict__ M,
                                                   int* __restrict__ top) {
  int bh  = blockIdx.x;
  int tid = threadIdx.x;
  int lane = tid & 63, wave = tid >> 6;
  __shared__ float vals[SL];
  __shared__ float wmax[4];
  __shared__ int   widx[4];
  for (int i = tid; i < SL; i += 256) vals[i] = M[(size_t)bh * SL + i];
  __syncthreads();
  for (int u = 0; u < NC; ++u) {
    float bm = -INFINITY; int bi = SL;
#pragma unroll
    for (int j = 0; j < SL / 256; ++j) {
      int i = tid + j * 256;
      float vv = vals[i];
      if (vv > bm) { bm = vv; bi = i; }
    }
#pragma unroll
    for (int off = 32; off > 0; off >>= 1) {
      float v2 = __shfl_xor(bm, off, 64);
      int   i2 = __shfl_xor(bi, off, 64);
      if (v2 > bm || (v2 == bm && i2 < bi)) { bm = v2; bi = i2; }
    }
    if (lane == 0) { wmax[wave] = bm; widx[wave] = bi; }
    __syncthreads();
    if (tid == 0) {
      float b0 = wmax[0]; int x0 = widx[0];
#pragma unroll
      for (int w = 1; w < 4; ++w) {
        float vw = wmax[w]; int iw = widx[w];
        if (vw > b0 || (vw == b0 && iw < x0)) { b0 = vw; x0 = iw; }
      }
      top[bh * NC + u] = x0;
      vals[x0] = -INFINITY;
    }
    __syncthreads();
  }
}

// ---------------- V mean, phase 1: per-chunk partials ----------------
__global__ __launch_bounds__(256) void vmean_part(const float* __restrict__ v,
                                                  float* __restrict__ partial) {
  int bh = blockIdx.x & 63;
  int chunk = blockIdx.x >> 6;
  int tid = threadIdx.x;
  int e = tid & 15, g = tid >> 4;
  const float* vb = v + ((size_t)bh * SL + chunk * 256) * EHD;
  float s = 0.f;
#pragma unroll
  for (int j = 0; j < 16; ++j) s += vb[(size_t)(j * 16 + g) * EHD + e];
  __shared__ float red[256];
  red[tid] = s; __syncthreads();
  for (int st = 128; st >= 16; st >>= 1) {
    if (tid < st) red[tid] += red[tid + st];
    __syncthreads();
  }
  if (tid < EHD) partial[(bh * 16 + chunk) * EHD + tid] = red[tid];
}

// ---------------- ctx = broadcast vmean (finish fused; float4 writes) -------------
__global__ __launch_bounds__(256) void fillctx_kernel(const float* __restrict__ partial,
                                                      float* __restrict__ ctx) {
  __shared__ float vm[EHD];
  int tid = threadIdx.x;
  int t0 = blockIdx.x * 256;
  int bh = t0 >> 14;
  if (tid < EHD) {
    float s = 0.f;
#pragma unroll
    for (int c = 0; c < 16; ++c) s += partial[(bh * 16 + c) * EHD + tid];
    vm[tid] = s * (1.0f / (float)SL);
  }
  __syncthreads();
  int t = t0 + tid;
  int e0 = (t & 3) * 4;
  *(float4*)(ctx + (size_t)t * 4) = make_float4(vm[e0], vm[e0 + 1], vm[e0 + 2], vm[e0 + 3]);
}

// ---------------- flash attention, KV-chunked: partials to pa ----------------
__global__ __launch_bounds__(256) void attn_flash(const float* __restrict__ q,
    const float* __restrict__ k, const float* __restrict__ v,
    const int* __restrict__ top, float* __restrict__ pa) {
  int bh = blockIdx.x & 63, ug = (blockIdx.x >> 6) & 3, chunk = blockIdx.x >> 8;
  int tid = threadIdx.x, wid = tid >> 6, lane = tid & 63;
  int base = ug * 7;
  int nq = (ug < 3) ? 7 : 6;
  bool has0 = (wid < nq);
  bool has1 = (wid + 4 < nq);
  int u0 = base + (has0 ? wid : 0);
  int u1 = base + (has1 ? wid + 4 : 0);
  int qi0 = top[bh * NC + u0];
  int qi1 = top[bh * NC + u1];
  float q0[16], q1[16];
  {
    const float* p0 = q + ((size_t)bh * SL + qi0) * EHD;
    const float* p1 = q + ((size_t)bh * SL + qi1) * EHD;
#pragma unroll
    for (int i = 0; i < 4; ++i) {
      float4 f = *(const float4*)(p0 + 4 * i);
      q0[4*i] = f.x; q0[4*i+1] = f.y; q0[4*i+2] = f.z; q0[4*i+3] = f.w;
      float4 g = *(const float4*)(p1 + 4 * i);
      q1[4*i] = g.x; q1[4*i+1] = g.y; q1[4*i+2] = g.z; q1[4*i+3] = g.w;
    }
  }
  float m0 = -INFINITY, m1 = -INFINITY, l0 = 0.f, l1 = 0.f;
  float a0[16], a1[16];
#pragma unroll
  for (int j = 0; j < 16; ++j) { a0[j] = 0.f; a1[j] = 0.f; }
  const float* kb = k + (size_t)bh * SL * EHD;
  const float* vb = v + (size_t)bh * SL * EHD;
  int row_base = chunk * (SL / ACH);
  for (int t = 0; t < SL / ACH / 64; ++t) {
    int ki = row_base + lane + (t << 6);
    float kr[16], vr[16];
    {
      const float* kp = kb + (size_t)ki * EHD;
      const float* vp = vb + (size_t)ki * EHD;
#pragma unroll
      for (int i = 0; i < 4; ++i) {
        float4 f = *(const float4*)(kp + 4 * i);
        kr[4*i] = f.x; kr[4*i+1] = f.y; kr[4*i+2] = f.z; kr[4*i+3] = f.w;
        float4 g = *(const float4*)(vp + 4 * i);
        vr[4*i] = g.x; vr[4*i+1] = g.y; vr[4*i+2] = g.z; vr[4*i+3] = g.w;
      }
    }
    float s0 = 0.f, s1 = 0.f;
#pragma unroll
    for (int j = 0; j < 16; ++j) { s0 += q0[j] * kr[j]; s1 += q1[j] * kr[j]; }
    s0 *= 0.25f; s1 *= 0.25f;
    {
      float d = s0 - m0;
      float e = expf(-fabsf(d));
      bool gt = d > 0.f;
      float c = gt ? e : 1.f;
      float p = gt ? 1.f : e;
      m0 = gt ? s0 : m0;
      l0 = l0 * c + p;
#pragma unroll
      for (int j = 0; j < 16; ++j) a0[j] = a0[j] * c + p * vr[j];
    }
    {
      float d = s1 - m1;
      float e = expf(-fabsf(d));
      bool gt = d > 0.f;
      float c = gt ? e : 1.f;
      float p = gt ? 1.f : e;
      m1 = gt ? s1 : m1;
      l1 = l1 * c + p;
#pragma unroll
      for (int j = 0; j < 16; ++j) a1[j] = a1[j] * c + p * vr[j];
    }
  }
#pragma unroll
  for (int off = 1; off < 64; off <<= 1) {
    {
      float mo = __shfl_xor(m0, off, 64);
      float lo_ = __shfl_xor(l0, off, 64);
      float mn = fmaxf(m0, mo);
      float cs = expf(m0 - mn), co = expf(mo - mn);
      l0 = l0 * cs + lo_ * co;
#pragma unroll
      for (int j = 0; j < 16; ++j) {
        float ao = __shfl_xor(a0[j], off, 64);
        a0[j] = a0[j] * cs + ao * co;
      }
      m0 = mn;
    }
    {
      float mo = __shfl_xor(m1, off, 64);
      float lo_ = __shfl_xor(l1, off, 64);
      float mn = fmaxf(m1, mo);
      float cs = expf(m1 - mn), co = expf(mo - mn);
      l1 = l1 * cs + lo_ * co;
#pragma unroll
      for (int j = 0; j < 16; ++j) {
        float ao = __shfl_xor(a1[j], off, 64);
        a1[j] = a1[j] * cs + ao * co;
      }
      m1 = mn;
    }
  }
  if (lane == 0 && has0) {
    float* o = pa + ((size_t)(bh * NC + u0) * ACH + chunk) * 18;
    o[0] = m0; o[1] = l0;
#pragma unroll
    for (int j = 0; j < 16; ++j) o[2 + j] = a0[j];
  }
  if (lane == 0 && has1) {
    float* o = pa + ((size_t)(bh * NC + u1) * ACH + chunk) * 18;
    o[0] = m1; o[1] = l1;
#pragma unroll
    for (int j = 0; j < 16; ++j) o[2 + j] = a1[j];
  }
}

// ---------------- merge attn partials -> ctx rows ----------------
__global__ __launch_bounds__(64) void attn_merge(const float* __restrict__ pa,
    const int* __restrict__ top, float* __restrict__ ctx) {
  int bh = blockIdx.x;
  int u = threadIdx.x;
  if (u >= NC) return;
  float m = -INFINITY, L = 0.f;
  float a[16];
#pragma unroll
  for (int j = 0; j < 16; ++j) a[j] = 0.f;
#pragma unroll
  for (int c = 0; c < ACH; ++c) {
    const float* p = pa + ((size_t)(bh * NC + u) * ACH + c) * 18;
    float pm = p[0], pl = p[1];
    float mn = fmaxf(m, pm);
    float cs = expf(m - mn), co = expf(pm - mn);
    L = L * cs + pl * co;
#pragma unroll
    for (int j = 0; j < 16; ++j) a[j] = a[j] * cs + p[2 + j] * co;
    m = mn;
  }
  int qi = top[bh * NC + u];
  float inv = 1.0f / L;
  float* o = ctx + ((size_t)bh * SL + qi) * EHD;
#pragma unroll
  for (int j = 0; j < 16; ++j) o[j] = a[j] * inv;
}

// ---------------- launch ----------------
extern "C" void kernel_launch(void* const* d_in, const int* in_sizes, int n_in,
                              void* d_out, int out_size, void* d_ws, size_t ws_size,
                              hipStream_t stream) {
  const float* x   = (const float*)d_in[0];
  const float* Wq  = (const float*)d_in[1];
  const float* bq  = (const float*)d_in[2];
  const float* Wk  = (const float*)d_in[3];
  const float* bk  = (const float*)d_in[4];
  const float* Wv  = (const float*)d_in[5];
  const float* bv  = (const float*)d_in[6];
  const float* Wo  = (const float*)d_in[7];
  const float* bo  = (const float*)d_in[8];
  const float* W1  = (const float*)d_in[9];
  const float* b1  = (const float*)d_in[10];
  const float* W2  = (const float*)d_in[11];
  const float* b2  = (const float*)d_in[12];
  const float* ln1w = (const float*)d_in[13];
  const float* ln1b = (const float*)d_in[14];
  const float* ln2w = (const float*)d_in[15];
  const float* ln2b = (const float*)d_in[16];
  const float* lnfw = (const float*)d_in[17];
  const float* lnfb = (const float*)d_in[18];
  const float* Wp  = (const float*)d_in[19];
  const float* bp  = (const float*)d_in[20];
  float* out = (float*)d_out;

  float* ws = (float*)d_ws;
  float* h     = ws;                      // 4194304
  float* q     = ws + 4194304;            // 4194304
  float* k     = ws + 8388608;            // 4194304
  float* v     = ws + 12582912;           // 4194304
  float* ctx   = ws + 16777216;           // 4194304
  float* partial = ws + 20971520;         // 16384
  float* pa    = ws + 20987904;           // 124416
  float* M     = ws + 23068672;           // 262144
  int*   top   = (int*)(ws + 23331840);
  uint32_t* bits = (uint32_t*)(ws + 23333888);
  f16* phi = (f16*)(ws + 23444480);

  transpose_x_kernel<<<dim3(SL / 32, DM / 32, NB), 256, 0, stream>>>(x, h);
  prep_weights<<<(PACK_TOTAL + 255) / 256, 256, 0, stream>>>(
      Wq, Wk, Wv, Wo, W1, W2, Wp, phi);

  for (int l = 0; l < NLAY; ++l) {
    size_t lb = (size_t)l * 81920;
    gen_bits_kernel<<<(SL * NC + 255) / 256, 256, 0, stream>>>(bits, l);
    gemm_fused<4, 8, 0, 0><<<NROWS / 64, 256, 0, stream>>>(
        h, phi + lb, bq + l * DM, bk + l * DM, bv + l * DM,
        q, k, v, nullptr, nullptr, nullptr);
    sampM_kernel<<<NBH * SL / 32, 256, 0, stream>>>(q, k, bits, M);
    topk_kernel<<<NBH, 256, 0, stream>>>(M, top);
    vmean_part<<<NBH * 16, 256, 0, stream>>>(v, partial);
    fillctx_kernel<<<NBH * SL * 4 / 256, 256, 0, stream>>>(partial, ctx);
    attn_flash<<<ACH * 256, 256, 0, stream>>>(q, k, v, top, pa);
    attn_merge<<<NBH, 64, 0, stream>>>(pa, top, ctx);
    gemm_fused<4, 8, 1, 1><<<NROWS / 64, 256, 0, stream>>>(
        ctx, phi + lb + 49152, bo + l * DM, nullptr, nullptr,
        h, nullptr, nullptr, ln1w + l * DM, ln1b + l * DM, h);
    gemm_ffn<<<NROWS / 64, 256, 0, stream>>>(
        h, phi + lb + 65536, phi + lb + 73728,
        b1 + l * DFF, b2 + l * DM, ln2w + l * DM, ln2b + l * DM, h);
  }

  gemm_fused<4, 8, 3, 3><<<NROWS / 64, 256, 0, stream>>>(
      h, phi + 409600, bp, nullptr, nullptr,
      out, nullptr, nullptr, lnfw, lnfb, nullptr);
}

// Round 15
// 940.772 us; speedup vs baseline: 1.0485x; 1.0485x over previous
//
#include <hip/hip_runtime.h>
#include <stdint.h>
#include <math.h>

#define DM   128
#define NH   8
#define EHD  16
#define NLAY 5
#define DFF  64
#define NREP 128
#define NB   8
#define SL   4096
#define NC   27
#define NBH  (NB*NH)      // 64
#define NROWS (NB*SL)     // 32768
#define ACH  4            // attn KV chunks

typedef _Float16 f16;
typedef f16 f16x8 __attribute__((ext_vector_type(8)));
typedef float f32x16 __attribute__((ext_vector_type(16)));

// ---------------- threefry2x32 (JAX-exact) ----------------
__device__ __forceinline__ uint32_t rotl32(uint32_t v, int d) {
  return (v << d) | (v >> (32 - d));
}

__device__ __forceinline__ void tf2x32(uint32_t k0, uint32_t k1,
                                       uint32_t x0, uint32_t x1,
                                       uint32_t &o0, uint32_t &o1) {
  uint32_t ks2 = k0 ^ k1 ^ 0x1BD11BDAu;
  x0 += k0; x1 += k1;
#define TFR(r) { x0 += x1; x1 = rotl32(x1, (r)); x1 ^= x0; }
  TFR(13) TFR(15) TFR(26) TFR(6)
  x0 += k1; x1 += ks2 + 1u;
  TFR(17) TFR(29) TFR(16) TFR(24)
  x0 += ks2; x1 += k0 + 2u;
  TFR(13) TFR(15) TFR(26) TFR(6)
  x0 += k0; x1 += k1 + 3u;
  TFR(17) TFR(29) TFR(16) TFR(24)
  x0 += k1; x1 += ks2 + 4u;
  TFR(13) TFR(15) TFR(26) TFR(6)
  x0 += ks2; x1 += k0 + 5u;
#undef TFR
  o0 = x0; o1 = x1;
}

// bits[i] for flat counter i = l*NC + u
__global__ void gen_bits_kernel(uint32_t* __restrict__ bits, int layer) {
  int i = blockIdx.x * blockDim.x + threadIdx.x;
  if (i >= SL * NC) return;
  uint32_t ka, kb, k2a, k2b, y0, y1;
  tf2x32(0u, 42u, 0u, (uint32_t)layer, ka, kb);
  tf2x32(ka, kb, 0u, 1u, k2a, k2b);
  tf2x32(k2a, k2b, 0u, (uint32_t)i, y0, y1);
  bits[i] = y0 ^ y1;
}

// ---------------- x[b,d,l] -> h[b,l,d], LDS-tiled ----------------
__global__ __launch_bounds__(256) void transpose_x_kernel(const float* __restrict__ x,
                                                          float* __restrict__ h) {
  __shared__ float t[32][33];
  int tid = threadIdx.x;
  int tx = tid & 31, ty = tid >> 5;
  int l0 = blockIdx.x * 32, d0 = blockIdx.y * 32, b = blockIdx.z;
#pragma unroll
  for (int j = 0; j < 4; ++j) {
    int d = d0 + ty + 8 * j;
    t[ty + 8 * j][tx] = x[((size_t)b * DM + d) * SL + l0 + tx];
  }
  __syncthreads();
#pragma unroll
  for (int j = 0; j < 4; ++j) {
    int l = l0 + ty + 8 * j;
    h[((size_t)b * SL + l) * DM + d0 + tx] = t[tx][ty + 8 * j];
  }
}

// ---------------- weight prep: fp32 -> f16 hi ----------------
#define PACK_TOTAL 425984
__global__ __launch_bounds__(256) void prep_weights(
    const float* __restrict__ Wq, const float* __restrict__ Wk,
    const float* __restrict__ Wv, const float* __restrict__ Wo,
    const float* __restrict__ W1, const float* __restrict__ W2,
    const float* __restrict__ Wp, f16* __restrict__ phi) {
  int idx = blockIdx.x * 256 + threadIdx.x;
  if (idx >= PACK_TOTAL) return;
  const float* src; int K, KS16, lsh; int f; bool transp = false;
  if (idx >= 409600) { f = idx - 409600; src = Wp; K = 128; KS16 = 8; lsh = 3; transp = true; }
  else {
    int layer = idx / 81920; int r = idx - layer * 81920;
    if      (r < 16384) { src = Wq + layer * 16384; f = r;         K = 128; KS16 = 8; lsh = 3; }
    else if (r < 32768) { src = Wk + layer * 16384; f = r - 16384; K = 128; KS16 = 8; lsh = 3; }
    else if (r < 49152) { src = Wv + layer * 16384; f = r - 32768; K = 128; KS16 = 8; lsh = 3; }
    else if (r < 65536) { src = Wo + layer * 16384; f = r - 49152; K = 128; KS16 = 8; lsh = 3; }
    else if (r < 73728) { src = W1 + layer * 8192;  f = r - 65536; K = 128; KS16 = 8; lsh = 3; }
    else                { src = W2 + layer * 8192;  f = r - 73728; K = 64;  KS16 = 4; lsh = 2; }
  }
  int j = f & 7, lane = (f >> 3) & 63, rest = f >> 9;
  int ks = rest & (KS16 - 1), nt = rest >> lsh;
  int n = nt * 32 + (lane & 31);
  int kk = ks * 16 + ((lane >> 5) & 1) * 8 + j;
  float x = transp ? src[(size_t)kk * 128 + n] : src[(size_t)n * K + kk];
  phi[idx] = (f16)x;
}

// ---------------- split-fp16 MFMA GEMM (2-pass: Ahi*Bhi + Alo*Bhi) ----------------
template<int NT32, int KS16, int SRC, int EPI>
__global__ __launch_bounds__(256, 2) void gemm_fused(
    const float* __restrict__ Asrc, const f16* __restrict__ phi,
    const float* __restrict__ bias0, const float* __restrict__ bias1,
    const float* __restrict__ bias2,
    float* out0, float* out1, float* out2,
    const float* __restrict__ gw, const float* __restrict__ gb,
    const float* hres) {
  constexpr int NGW = NT32 / 2;
  constexpr int K = KS16 * 16;
  __shared__ f16x8 Alds[2 * 2 * KS16 * 64];
  __shared__ f16x8 Blds[NT32 * KS16 * 64];
  __shared__ float red[64 * 4];
  int tid = threadIdx.x, lane = tid & 63, wid = tid >> 6;
  int mg = wid >> 1, ng = wid & 1;
  int row0 = blockIdx.x * 64;

  // ---- stage A (hi+lo) ----
  if constexpr (SRC == 0 || SRC == 1) {
    constexpr int OCT = 64 * (K / 8);
    for (int o = tid; o < OCT; o += 256) {
      int row = o / (K / 8);
      int k0 = (o % (K / 8)) * 8;
      float4 f0, f1;
      if constexpr (SRC == 0) {
        const float* s = Asrc + (size_t)(row0 + row) * K + k0;
        f0 = *(const float4*)(s);
        f1 = *(const float4*)(s + 4);
      } else {
        int gr = row0 + row; int bb = gr >> 12, ll = gr & (SL - 1);
        int head = k0 >> 4, e0 = k0 & 15;
        const float* s = Asrc + (((size_t)(bb * NH + head) * SL + ll) * EHD + e0);
        f0 = *(const float4*)(s);
        f1 = *(const float4*)(s + 4);
      }
      f16x8 vh, vl;
      float xs[8] = {f0.x, f0.y, f0.z, f0.w, f1.x, f1.y, f1.z, f1.w};
#pragma unroll
      for (int j = 0; j < 8; ++j) {
        f16 hh = (f16)xs[j];
        vh[j] = hh;
        vl[j] = (f16)(xs[j] - (float)hh);
      }
      int al = (row & 31) | (((k0 >> 3) & 1) << 5);
      int ks = k0 >> 4, mt = row >> 5;
      Alds[((0 * 2 + mt) * KS16 + ks) * 64 + al] = vh;
      Alds[((1 * 2 + mt) * KS16 + ks) * 64 + al] = vl;
    }
  } else {  // SRC == 3 : h rows + final LayerNorm before packing
    int row = tid >> 2, q4 = tid & 3;
    const float* s = Asrc + (size_t)(row0 + row) * 128 + q4 * 32;
    float r[32];
#pragma unroll
    for (int i = 0; i < 8; ++i) {
      float4 f = *(const float4*)(s + 4 * i);
      r[4 * i] = f.x; r[4 * i + 1] = f.y; r[4 * i + 2] = f.z; r[4 * i + 3] = f.w;
    }
    float sm = 0.f, s2 = 0.f;
#pragma unroll
    for (int i = 0; i < 32; ++i) { sm += r[i]; s2 += r[i] * r[i]; }
    sm += __shfl_xor(sm, 1, 4); sm += __shfl_xor(sm, 2, 4);
    s2 += __shfl_xor(s2, 1, 4); s2 += __shfl_xor(s2, 2, 4);
    float mean = sm * (1.f / 128.f);
    float var = s2 * (1.f / 128.f) - mean * mean;
    float rstd = 1.0f / sqrtf(var + 1e-5f);
#pragma unroll
    for (int i = 0; i < 32; ++i) {
      int kk = q4 * 32 + i;
      r[i] = (r[i] - mean) * rstd * gw[kk] + gb[kk];
    }
#pragma unroll
    for (int i = 0; i < 4; ++i) {
      int k0 = q4 * 32 + i * 8;
      f16x8 vh, vl;
#pragma unroll
      for (int j = 0; j < 8; ++j) {
        float x = r[8 * i + j];
        f16 hh = (f16)x;
        vh[j] = hh;
        vl[j] = (f16)(x - (float)hh);
      }
      int al = (row & 31) | (((k0 >> 3) & 1) << 5);
      int ks = k0 >> 4, mt = row >> 5;
      Alds[((0 * 2 + mt) * KS16 + ks) * 64 + al] = vh;
      Alds[((1 * 2 + mt) * KS16 + ks) * 64 + al] = vl;
    }
  }

  constexpr int NMAT = (EPI == 0) ? 3 : 1;
  constexpr int BCNT = NT32 * KS16 * 64;  // f16x8 (=float4) count

#define STAGE_B(SRCPTR)                                        \
  {                                                            \
    const float4* bsrc = (const float4*)(SRCPTR);              \
    float4* bdst = (float4*)Blds;                              \
    _Pragma("unroll")                                          \
    for (int i = 0; i < BCNT / 256; ++i) bdst[tid + i * 256] = bsrc[tid + i * 256]; \
  }

#define GEMM_PASS(ASEL)                                                         \
  _Pragma("unroll")                                                             \
  for (int ks = 0; ks < KS16; ++ks) {                                           \
    f16x8 afr = Alds[(((ASEL) * 2 + mg) * KS16 + ks) * 64 + lane];              \
    _Pragma("unroll")                                                           \
    for (int g = 0; g < NGW; ++g) {                                             \
      f16x8 bfr = Blds[((ng * NGW + g) * KS16 + ks) * 64 + lane];               \
      acc[g] = __builtin_amdgcn_mfma_f32_32x32x16_f16(afr, bfr, acc[g], 0, 0, 0); \
    }                                                                           \
  }

  for (int m = 0; m < NMAT; ++m) {
    if (m) __syncthreads();
    STAGE_B(phi + m * 16384)
    __syncthreads();
    f32x16 acc[NGW];
#pragma unroll
    for (int g = 0; g < NGW; ++g)
#pragma unroll
      for (int j = 0; j < 16; ++j) acc[g][j] = 0.f;
    GEMM_PASS(0)
    GEMM_PASS(1)

    // ---- epilogue ----
    int hi4 = 4 * (lane >> 5);
    if constexpr (EPI == 0) {
      const float* bm = (m == 0) ? bias0 : (m == 1) ? bias1 : bias2;
      float* om = (m == 0) ? out0 : (m == 1) ? out1 : out2;
#pragma unroll
      for (int g = 0; g < NGW; ++g) {
        int col = ng * (NGW * 32) + g * 32 + (lane & 31);
        float bv = bm[col];
        int head = col >> 4, e = col & 15;
#pragma unroll
        for (int reg = 0; reg < 16; ++reg) {
          int row_l = (reg & 3) + 8 * (reg >> 2) + hi4;
          int grow = row0 + mg * 32 + row_l;
          int bb = grow >> 12, ll = grow & (SL - 1);
          om[((size_t)(bb * NH + head) * SL + ll) * EHD + e] = acc[g][reg] + bv;
        }
      }
    } else if constexpr (EPI == 3) {
#pragma unroll
      for (int g = 0; g < NGW; ++g) {
        int col = ng * (NGW * 32) + g * 32 + (lane & 31);
        float bv = bias0[col];
#pragma unroll
        for (int reg = 0; reg < 16; ++reg) {
          int row_l = (reg & 3) + 8 * (reg >> 2) + hi4;
          int grow = row0 + mg * 32 + row_l;
          int bb = grow >> 12, ll = grow & (SL - 1);
          out0[((size_t)(bb * NREP + col)) * SL + ll] = acc[g][reg] + bv;
        }
      }
    } else {  // EPI == 1: residual + LayerNorm -> h
      float bv[2], gwv[2], gbv[2];
#pragma unroll
      for (int g = 0; g < NGW; ++g) {
        int col = ng * (NGW * 32) + g * 32 + (lane & 31);
        bv[g] = bias0[col]; gwv[g] = gw[col]; gbv[g] = gb[col];
      }
      float ps[16], pq[16];
#pragma unroll
      for (int reg = 0; reg < 16; ++reg) {
        int row_l = (reg & 3) + 8 * (reg >> 2) + hi4;
        int grow = row0 + mg * 32 + row_l;
        float vsum = 0.f, qsum = 0.f;
#pragma unroll
        for (int g = 0; g < NGW; ++g) {
          int col = ng * (NGW * 32) + g * 32 + (lane & 31);
          float t = acc[g][reg] + bv[g] + hres[(size_t)grow * DM + col];
          acc[g][reg] = t;
          vsum += t; qsum += t * t;
        }
        vsum += __shfl_xor(vsum, 1, 32); qsum += __shfl_xor(qsum, 1, 32);
        vsum += __shfl_xor(vsum, 2, 32); qsum += __shfl_xor(qsum, 2, 32);
        vsum += __shfl_xor(vsum, 4, 32); qsum += __shfl_xor(qsum, 4, 32);
        vsum += __shfl_xor(vsum, 8, 32); qsum += __shfl_xor(qsum, 8, 32);
        vsum += __shfl_xor(vsum, 16, 32); qsum += __shfl_xor(qsum, 16, 32);
        ps[reg] = vsum; pq[reg] = qsum;
      }
      __syncthreads();
      if ((lane & 31) == 0) {
#pragma unroll
        for (int reg = 0; reg < 16; ++reg) {
          int row_l = (reg & 3) + 8 * (reg >> 2) + hi4;
          int rl = mg * 32 + row_l;
          red[rl * 4 + ng * 2 + 0] = ps[reg];
          red[rl * 4 + ng * 2 + 1] = pq[reg];
        }
      }
      __syncthreads();
#pragma unroll
      for (int reg = 0; reg < 16; ++reg) {
        int row_l = (reg & 3) + 8 * (reg >> 2) + hi4;
        int rl = mg * 32 + row_l;
        int grow = row0 + rl;
        float st = red[rl * 4 + 0] + red[rl * 4 + 2];
        float qt = red[rl * 4 + 1] + red[rl * 4 + 3];
        float mean = st * (1.f / 128.f);
        float var = qt * (1.f / 128.f) - mean * mean;
        float rstd = 1.0f / sqrtf(var + 1e-5f);
#pragma unroll
        for (int g = 0; g < NGW; ++g) {
          int col = ng * (NGW * 32) + g * 32 + (lane & 31);
          out0[(size_t)grow * DM + col] = (acc[g][reg] - mean) * rstd * gwv[g] + gbv[g];
        }
      }
    }
  }
#undef STAGE_B
#undef GEMM_PASS
}

// ---------------- fused FFN (2-pass GEMMs) ----------------
__global__ __launch_bounds__(256, 2) void gemm_ffn(
    const float* __restrict__ h,
    const f16* __restrict__ w1hi, const f16* __restrict__ w2hi,
    const float* __restrict__ b1, const float* __restrict__ b2,
    const float* __restrict__ gw, const float* __restrict__ gb,
    float* __restrict__ hout) {
  __shared__ f16x8 AldsH[2 * 2 * 8 * 64];   // 32KB
  __shared__ f16x8 Blds1[2 * 8 * 64];       // 16KB
  __shared__ float ybuf[64 * 64];           // 16KB
  __shared__ float red[64 * 4];
  f16x8* Alds2 = AldsH;
  f16x8* Blds2 = AldsH + 1024;
  int tid = threadIdx.x, lane = tid & 63, wid = tid >> 6;
  int mg = wid >> 1, ng = wid & 1;
  int row0 = blockIdx.x * 64;
  int hi4 = 4 * (lane >> 5);

  for (int o = tid; o < 64 * 16; o += 256) {
    int row = o >> 4;
    int k0 = (o & 15) * 8;
    const float* s = h + (size_t)(row0 + row) * 128 + k0;
    float4 f0 = *(const float4*)(s);
    float4 f1 = *(const float4*)(s + 4);
    f16x8 vh, vl;
    float xs[8] = {f0.x, f0.y, f0.z, f0.w, f1.x, f1.y, f1.z, f1.w};
#pragma unroll
    for (int j = 0; j < 8; ++j) {
      f16 hh = (f16)xs[j];
      vh[j] = hh;
      vl[j] = (f16)(xs[j] - (float)hh);
    }
    int al = (row & 31) | (((k0 >> 3) & 1) << 5);
    int ks = k0 >> 4, mt = row >> 5;
    AldsH[((0 * 2 + mt) * 8 + ks) * 64 + al] = vh;
    AldsH[((1 * 2 + mt) * 8 + ks) * 64 + al] = vl;
  }
  {
    const float4* bsrc = (const float4*)w1hi;
    float4* bdst = (float4*)Blds1;
#pragma unroll
    for (int i = 0; i < 4; ++i) bdst[tid + i * 256] = bsrc[tid + i * 256];
  }
  __syncthreads();
  f32x16 acc1;
#pragma unroll
  for (int j = 0; j < 16; ++j) acc1[j] = 0.f;
#pragma unroll
  for (int asel = 0; asel < 2; ++asel)
#pragma unroll
    for (int ks = 0; ks < 8; ++ks) {
      f16x8 afr = AldsH[((asel * 2 + mg) * 8 + ks) * 64 + lane];
      f16x8 bfr = Blds1[(ng * 8 + ks) * 64 + lane];
      acc1 = __builtin_amdgcn_mfma_f32_32x32x16_f16(afr, bfr, acc1, 0, 0, 0);
    }
  {
    int col = ng * 32 + (lane & 31);
    float bv = b1[col];
    const float is2 = 0.707106781186547524f;
#pragma unroll
    for (int reg = 0; reg < 16; ++reg) {
      int row_l = (reg & 3) + 8 * (reg >> 2) + hi4 + mg * 32;
      float a = acc1[reg] + bv;
      ybuf[row_l * 64 + col] = 0.5f * a * (1.f + erff(a * is2));
    }
  }
  __syncthreads();   // ybuf complete AND all GEMM1 reads of AldsH/Blds1 done
  for (int o = tid; o < 64 * 8; o += 256) {
    int row = o >> 3;
    int k0 = (o & 7) * 8;
    f16x8 vh, vl;
#pragma unroll
    for (int j = 0; j < 8; ++j) {
      float x = ybuf[row * 64 + k0 + j];
      f16 hh = (f16)x;
      vh[j] = hh;
      vl[j] = (f16)(x - (float)hh);
    }
    int al = (row & 31) | (((k0 >> 3) & 1) << 5);
    int ks = k0 >> 4, mt = row >> 5;
    Alds2[((0 * 2 + mt) * 4 + ks) * 64 + al] = vh;
    Alds2[((1 * 2 + mt) * 4 + ks) * 64 + al] = vl;
  }
  {
    const float4* bsrc = (const float4*)w2hi;
    float4* bdst = (float4*)Blds2;
#pragma unroll
    for (int i = 0; i < 4; ++i) bdst[tid + i * 256] = bsrc[tid + i * 256];
  }
  __syncthreads();
  f32x16 acc[2];
#pragma unroll
  for (int g = 0; g < 2; ++g)
#pragma unroll
    for (int j = 0; j < 16; ++j) acc[g][j] = 0.f;
#pragma unroll
  for (int asel = 0; asel < 2; ++asel)
#pragma unroll
    for (int ks = 0; ks < 4; ++ks) {
      f16x8 afr = Alds2[((asel * 2 + mg) * 4 + ks) * 64 + lane];
#pragma unroll
      for (int g = 0; g < 2; ++g) {
        f16x8 bfr = Blds2[((ng * 2 + g) * 4 + ks) * 64 + lane];
        acc[g] = __builtin_amdgcn_mfma_f32_32x32x16_f16(afr, bfr, acc[g], 0, 0, 0);
      }
    }
  {
    float bv[2], gwv[2], gbv[2];
#pragma unroll
    for (int g = 0; g < 2; ++g) {
      int col = ng * 64 + g * 32 + (lane & 31);
      bv[g] = b2[col]; gwv[g] = gw[col]; gbv[g] = gb[col];
    }
    float ps[16], pq[16];
#pragma unroll
    for (int reg = 0; reg < 16; ++reg) {
      int row_l = (reg & 3) + 8 * (reg >> 2) + hi4;
      int grow = row0 + mg * 32 + row_l;
      float vsum = 0.f, qsum = 0.f;
#pragma unroll
      for (int g = 0; g < 2; ++g) {
        int col = ng * 64 + g * 32 + (lane & 31);
        float t = acc[g][reg] + bv[g] + h[(size_t)grow * DM + col];
        acc[g][reg] = t;
        vsum += t; qsum += t * t;
      }
      vsum += __shfl_xor(vsum, 1, 32); qsum += __shfl_xor(qsum, 1, 32);
      vsum += __shfl_xor(vsum, 2, 32); qsum += __shfl_xor(qsum, 2, 32);
      vsum += __shfl_xor(vsum, 4, 32); qsum += __shfl_xor(qsum, 4, 32);
      vsum += __shfl_xor(vsum, 8, 32); qsum += __shfl_xor(qsum, 8, 32);
      vsum += __shfl_xor(vsum, 16, 32); qsum += __shfl_xor(qsum, 16, 32);
      ps[reg] = vsum; pq[reg] = qsum;
    }
    __syncthreads();
    if ((lane & 31) == 0) {
#pragma unroll
      for (int reg = 0; reg < 16; ++reg) {
        int row_l = (reg & 3) + 8 * (reg >> 2) + hi4;
        int rl = mg * 32 + row_l;
        red[rl * 4 + ng * 2 + 0] = ps[reg];
        red[rl * 4 + ng * 2 + 1] = pq[reg];
      }
    }
    __syncthreads();
#pragma unroll
    for (int reg = 0; reg < 16; ++reg) {
      int row_l = (reg & 3) + 8 * (reg >> 2) + hi4;
      int rl = mg * 32 + row_l;
      int grow = row0 + rl;
      float st = red[rl * 4 + 0] + red[rl * 4 + 2];
      float qt = red[rl * 4 + 1] + red[rl * 4 + 3];
      float mean = st * (1.f / 128.f);
      float var = qt * (1.f / 128.f) - mean * mean;
      float rstd = 1.0f / sqrtf(var + 1e-5f);
#pragma unroll
      for (int g = 0; g < 2; ++g) {
        int col = ng * 64 + g * 32 + (lane & 31);
        hout[(size_t)grow * DM + col] = (acc[g][reg] - mean) * rstd * gwv[g] + gbv[g];
      }
    }
  }
}

// ---------------- sampled scores -> M (R13 pair layout: 2 lanes/sample) -------
__global__ __launch_bounds__(256) void sampM_kernel(const float* __restrict__ q,
    const float* __restrict__ k, const uint32_t* __restrict__ bits,
    float* __restrict__ M) {
  int tid = threadIdx.x;
  int wave = tid >> 6, lane = tid & 63;
  int bh = blockIdx.x & 63;
  int l = (blockIdx.x >> 6) * 4 + wave;
  int u = lane >> 1;
  bool act = (u < NC);
  int uc = act ? u : 0;
  int ki = (int)(bits[l * NC + uc] & (SL - 1));   // pair lanes same addr -> 1 lookup
  int h8 = (lane & 1) * 8;
  const float* kr = k + ((size_t)bh * SL + ki) * EHD + h8;
  float4 k0 = *(const float4*)(kr);
  float4 k1 = *(const float4*)(kr + 4);
  const float* qr = q + ((size_t)bh * SL + l) * EHD + h8;
  float4 q0 = *(const float4*)(qr);
  float4 q1 = *(const float4*)(qr + 4);
  float s = q0.x*k0.x + q0.y*k0.y + q0.z*k0.z + q0.w*k0.w
          + q1.x*k1.x + q1.y*k1.y + q1.z*k1.z + q1.w*k1.w;
  s += __shfl_xor(s, 1, 64);                      // both pair lanes hold full dot
  float mval = act ? s : -INFINITY;
  float sval = (act && (lane & 1) == 0) ? s : 0.f;
#pragma unroll
  for (int off = 2; off < 64; off <<= 1) {        // skip off=1: pairs identical
    mval = fmaxf(mval, __shfl_xor(mval, off, 64));
    sval += __shfl_xor(sval, off, 64);
  }
  if (lane == 0) M[(size_t)bh * SL + l] = mval - sval * (1.0f / (float)SL);
}

// ---------------- top-k (iterative argmax, wave butterfly, stable ties) ----------------
__global__ __launch_bounds__(256) void topk_kernel(const float* __restrict__ M,
                                                   int* __restrict__ top) {
  int bh  = blockIdx.x;
  int tid = threadIdx.x;
  int lane = tid & 63, wave = tid >> 6;
  __shared__ float vals[SL];
  __shared__ float wmax[4];
  __shared__ int   widx[4];
  for (int i = tid; i < SL; i += 256) vals[i] = M[(size_t)bh * SL + i];
  __syncthreads();
  for (int u = 0; u < NC; ++u) {
    float bm = -INFINITY; int bi = SL;
#pragma unroll
    for (int j = 0; j < SL / 256; ++j) {
      int i = tid + j * 256;
      float vv = vals[i];
      if (vv > bm) { bm = vv; bi = i; }
    }
#pragma unroll
    for (int off = 32; off > 0; off >>= 1) {
      float v2 = __shfl_xor(bm, off, 64);
      int   i2 = __shfl_xor(bi, off, 64);
      if (v2 > bm || (v2 == bm && i2 < bi)) { bm = v2; bi = i2; }
    }
    if (lane == 0) { wmax[wave] = bm; widx[wave] = bi; }
    __syncthreads();
    if (tid == 0) {
      float b0 = wmax[0]; int x0 = widx[0];
#pragma unroll
      for (int w = 1; w < 4; ++w) {
        float vw = wmax[w]; int iw = widx[w];
        if (vw > b0 || (vw == b0 && iw < x0)) { b0 = vw; x0 = iw; }
      }
      top[bh * NC + u] = x0;
      vals[x0] = -INFINITY;
    }
    __syncthreads();
  }
}

// ---------------- V mean, phase 1: per-chunk partials ----------------
__global__ __launch_bounds__(256) void vmean_part(const float* __restrict__ v,
                                                  float* __restrict__ partial) {
  int bh = blockIdx.x & 63;
  int chunk = blockIdx.x >> 6;
  int tid = threadIdx.x;
  int e = tid & 15, g = tid >> 4;
  const float* vb = v + ((size_t)bh * SL + chunk * 256) * EHD;
  float s = 0.f;
#pragma unroll
  for (int j = 0; j < 16; ++j) s += vb[(size_t)(j * 16 + g) * EHD + e];
  __shared__ float red[256];
  red[tid] = s; __syncthreads();
  for (int st = 128; st >= 16; st >>= 1) {
    if (tid < st) red[tid] += red[tid + st];
    __syncthreads();
  }
  if (tid < EHD) partial[(bh * 16 + chunk) * EHD + tid] = red[tid];
}

// ---------------- ctx = broadcast vmean (finish fused; float4 writes) -------------
__global__ __launch_bounds__(256) void fillctx_kernel(const float* __restrict__ partial,
                                                      float* __restrict__ ctx) {
  __shared__ float vm[EHD];
  int tid = threadIdx.x;
  int t0 = blockIdx.x * 256;
  int bh = t0 >> 14;
  if (tid < EHD) {
    float s = 0.f;
#pragma unroll
    for (int c = 0; c < 16; ++c) s += partial[(bh * 16 + c) * EHD + tid];
    vm[tid] = s * (1.0f / (float)SL);
  }
  __syncthreads();
  int t = t0 + tid;
  int e0 = (t & 3) * 4;
  *(float4*)(ctx + (size_t)t * 4) = make_float4(vm[e0], vm[e0 + 1], vm[e0 + 2], vm[e0 + 3]);
}

// ---------------- flash attention, KV-chunked: partials to pa ----------------
__global__ __launch_bounds__(256) void attn_flash(const float* __restrict__ q,
    const float* __restrict__ k, const float* __restrict__ v,
    const int* __restrict__ top, float* __restrict__ pa) {
  int bh = blockIdx.x & 63, ug = (blockIdx.x >> 6) & 3, chunk = blockIdx.x >> 8;
  int tid = threadIdx.x, wid = tid >> 6, lane = tid & 63;
  int base = ug * 7;
  int nq = (ug < 3) ? 7 : 6;
  bool has0 = (wid < nq);
  bool has1 = (wid + 4 < nq);
  int u0 = base + (has0 ? wid : 0);
  int u1 = base + (has1 ? wid + 4 : 0);
  int qi0 = top[bh * NC + u0];
  int qi1 = top[bh * NC + u1];
  float q0[16], q1[16];
  {
    const float* p0 = q + ((size_t)bh * SL + qi0) * EHD;
    const float* p1 = q + ((size_t)bh * SL + qi1) * EHD;
#pragma unroll
    for (int i = 0; i < 4; ++i) {
      float4 f = *(const float4*)(p0 + 4 * i);
      q0[4*i] = f.x; q0[4*i+1] = f.y; q0[4*i+2] = f.z; q0[4*i+3] = f.w;
      float4 g = *(const float4*)(p1 + 4 * i);
      q1[4*i] = g.x; q1[4*i+1] = g.y; q1[4*i+2] = g.z; q1[4*i+3] = g.w;
    }
  }
  float m0 = -INFINITY, m1 = -INFINITY, l0 = 0.f, l1 = 0.f;
  float a0[16], a1[16];
#pragma unroll
  for (int j = 0; j < 16; ++j) { a0[j] = 0.f; a1[j] = 0.f; }
  const float* kb = k + (size_t)bh * SL * EHD;
  const float* vb = v + (size_t)bh * SL * EHD;
  int row_base = chunk * (SL / ACH);
  for (int t = 0; t < SL / ACH / 64; ++t) {
    int ki = row_base + lane + (t << 6);
    float kr[16], vr[16];
    {
      const float* kp = kb + (size_t)ki * EHD;
      const float* vp = vb + (size_t)ki * EHD;
#pragma unroll
      for (int i = 0; i < 4; ++i) {
        float4 f = *(const float4*)(kp + 4 * i);
        kr[4*i] = f.x; kr[4*i+1] = f.y; kr[4*i+2] = f.z; kr[4*i+3] = f.w;
        float4 g = *(const float4*)(vp + 4 * i);
        vr[4*i] = g.x; vr[4*i+1] = g.y; vr[4*i+2] = g.z; vr[4*i+3] = g.w;
      }
    }
    float s0 = 0.f, s1 = 0.f;
#pragma unroll
    for (int j = 0; j < 16; ++j) { s0 += q0[j] * kr[j]; s1 += q1[j] * kr[j]; }
    s0 *= 0.25f; s1 *= 0.25f;
    {
      float d = s0 - m0;
      float e = expf(-fabsf(d));
      bool gt = d > 0.f;
      float c = gt ? e : 1.f;
      float p = gt ? 1.f : e;
      m0 = gt ? s0 : m0;
      l0 = l0 * c + p;
#pragma unroll
      for (int j = 0; j < 16; ++j) a0[j] = a0[j] * c + p * vr[j];
    }
    {
      float d = s1 - m1;
      float e = expf(-fabsf(d));
      bool gt = d > 0.f;
      float c = gt ? e : 1.f;
      float p = gt ? 1.f : e;
      m1 = gt ? s1 : m1;
      l1 = l1 * c + p;
#pragma unroll
      for (int j = 0; j < 16; ++j) a1[j] = a1[j] * c + p * vr[j];
    }
  }
#pragma unroll
  for (int off = 1; off < 64; off <<= 1) {
    {
      float mo = __shfl_xor(m0, off, 64);
      float lo_ = __shfl_xor(l0, off, 64);
      float mn = fmaxf(m0, mo);
      float cs = expf(m0 - mn), co = expf(mo - mn);
      l0 = l0 * cs + lo_ * co;
#pragma unroll
      for (int j = 0; j < 16; ++j) {
        float ao = __shfl_xor(a0[j], off, 64);
        a0[j] = a0[j] * cs + ao * co;
      }
      m0 = mn;
    }
    {
      float mo = __shfl_xor(m1, off, 64);
      float lo_ = __shfl_xor(l1, off, 64);
      float mn = fmaxf(m1, mo);
      float cs = expf(m1 - mn), co = expf(mo - mn);
      l1 = l1 * cs + lo_ * co;
#pragma unroll
      for (int j = 0; j < 16; ++j) {
        float ao = __shfl_xor(a1[j], off, 64);
        a1[j] = a1[j] * cs + ao * co;
      }
      m1 = mn;
    }
  }
  if (lane == 0 && has0) {
    float* o = pa + ((size_t)(bh * NC + u0) * ACH + chunk) * 18;
    o[0] = m0; o[1] = l0;
#pragma unroll
    for (int j = 0; j < 16; ++j) o[2 + j] = a0[j];
  }
  if (lane == 0 && has1) {
    float* o = pa + ((size_t)(bh * NC + u1) * ACH + chunk) * 18;
    o[0] = m1; o[1] = l1;
#pragma unroll
    for (int j = 0; j < 16; ++j) o[2 + j] = a1[j];
  }
}

// ---------------- merge attn partials -> ctx rows ----------------
__global__ __launch_bounds__(64) void attn_merge(const float* __restrict__ pa,
    const int* __restrict__ top, float* __restrict__ ctx) {
  int bh = blockIdx.x;
  int u = threadIdx.x;
  if (u >= NC) return;
  float m = -INFINITY, L = 0.f;
  float a[16];
#pragma unroll
  for (int j = 0; j < 16; ++j) a[j] = 0.f;
#pragma unroll
  for (int c = 0; c < ACH; ++c) {
    const float* p = pa + ((size_t)(bh * NC + u) * ACH + c) * 18;
    float pm = p[0], pl = p[1];
    float mn = fmaxf(m, pm);
    float cs = expf(m - mn), co = expf(pm - mn);
    L = L * cs + pl * co;
#pragma unroll
    for (int j = 0; j < 16; ++j) a[j] = a[j] * cs + p[2 + j] * co;
    m = mn;
  }
  int qi = top[bh * NC + u];
  float inv = 1.0f / L;
  float* o = ctx + ((size_t)bh * SL + qi) * EHD;
#pragma unroll
  for (int j = 0; j < 16; ++j) o[j] = a[j] * inv;
}

// ---------------- launch ----------------
extern "C" void kernel_launch(void* const* d_in, const int* in_sizes, int n_in,
                              void* d_out, int out_size, void* d_ws, size_t ws_size,
                              hipStream_t stream) {
  const float* x   = (const float*)d_in[0];
  const float* Wq  = (const float*)d_in[1];
  const float* bq  = (const float*)d_in[2];
  const float* Wk  = (const float*)d_in[3];
  const float* bk  = (const float*)d_in[4];
  const float* Wv  = (const float*)d_in[5];
  const float* bv  = (const float*)d_in[6];
  const float* Wo  = (const float*)d_in[7];
  const float* bo  = (const float*)d_in[8];
  const float* W1  = (const float*)d_in[9];
  const float* b1  = (const float*)d_in[10];
  const float* W2  = (const float*)d_in[11];
  const float* b2  = (const float*)d_in[12];
  const float* ln1w = (const float*)d_in[13];
  const float* ln1b = (const float*)d_in[14];
  const float* ln2w = (const float*)d_in[15];
  const float* ln2b = (const float*)d_in[16];
  const float* lnfw = (const float*)d_in[17];
  const float* lnfb = (const float*)d_in[18];
  const float* Wp  = (const float*)d_in[19];
  const float* bp  = (const float*)d_in[20];
  float* out = (float*)d_out;

  float* ws = (float*)d_ws;
  float* h     = ws;                      // 4194304
  float* q     = ws + 4194304;            // 4194304
  float* k     = ws + 8388608;            // 4194304
  float* v     = ws + 12582912;           // 4194304
  float* ctx   = ws + 16777216;           // 4194304
  float* partial = ws + 20971520;         // 16384
  float* pa    = ws + 20987904;           // 124416
  float* M     = ws + 23068672;           // 262144
  int*   top   = (int*)(ws + 23331840);
  uint32_t* bits = (uint32_t*)(ws + 23333888);
  f16* phi = (f16*)(ws + 23444480);

  transpose_x_kernel<<<dim3(SL / 32, DM / 32, NB), 256, 0, stream>>>(x, h);
  prep_weights<<<(PACK_TOTAL + 255) / 256, 256, 0, stream>>>(
      Wq, Wk, Wv, Wo, W1, W2, Wp, phi);

  for (int l = 0; l < NLAY; ++l) {
    size_t lb = (size_t)l * 81920;
    gen_bits_kernel<<<(SL * NC + 255) / 256, 256, 0, stream>>>(bits, l);
    gemm_fused<4, 8, 0, 0><<<NROWS / 64, 256, 0, stream>>>(
        h, phi + lb, bq + l * DM, bk + l * DM, bv + l * DM,
        q, k, v, nullptr, nullptr, nullptr);
    sampM_kernel<<<NBH * SL / 4, 256, 0, stream>>>(q, k, bits, M);
    topk_kernel<<<NBH, 256, 0, stream>>>(M, top);
    vmean_part<<<NBH * 16, 256, 0, stream>>>(v, partial);
    fillctx_kernel<<<NBH * SL * 4 / 256, 256, 0, stream>>>(partial, ctx);
    attn_flash<<<ACH * 256, 256, 0, stream>>>(q, k, v, top, pa);
    attn_merge<<<NBH, 64, 0, stream>>>(pa, top, ctx);
    gemm_fused<4, 8, 1, 1><<<NROWS / 64, 256, 0, stream>>>(
        ctx, phi + lb + 49152, bo + l * DM, nullptr, nullptr,
        h, nullptr, nullptr, ln1w + l * DM, ln1b + l * DM, h);
    gemm_ffn<<<NROWS / 64, 256, 0, stream>>>(
        h, phi + lb + 65536, phi + lb + 73728,
        b1 + l * DFF, b2 + l * DM, ln2w + l * DM, ln2b + l * DM, h);
  }

  gemm_fused<4, 8, 3, 3><<<NROWS / 64, 256, 0, stream>>>(
      h, phi + 409600, bp, nullptr, nullptr,
      out, nullptr, nullptr, lnfw, lnfb, nullptr);
}